// Round 6
// baseline (292.829 us; speedup 1.0000x reference)
//
#include <hip/hip_runtime.h>
#include <hip/hip_cooperative_groups.h>
namespace cg = cooperative_groups;

#define HH 192
#define WW 192
#define HW 36864          // 192*192
#define NPIX 2359296      // 64*192*192
#define NEG (-1.0e30f)

// ---------------- fused conv: p = sigmoid(conv(relu(conv(grid)+hb))+pb) ----------------
// Proven rounds 4/5. One thread per float4 of p; h recomputed redundantly.
__global__ __launch_bounds__(256) void k_conv_fused(const float* __restrict__ X,
                                                    const float* __restrict__ hw9,
                                                    const float* __restrict__ hb,
                                                    const float* __restrict__ pw9,
                                                    const float* __restrict__ pb,
                                                    float* __restrict__ p_out) {
  int idx = blockIdx.x * 256 + threadIdx.x;
  if (idx >= NPIX / 4) return;
  int b = idx / (HW / 4);
  int rem = idx - b * (HW / 4);
  int y = rem / 48;
  int ch = rem - y * 48;
  int x0 = ch * 4;
  const float* g = X + (size_t)b * (2 * HW);  // grid = channel 0

  float gr[5][8];
#pragma unroll
  for (int ry = 0; ry < 5; ++ry) {
    int yy = y - 2 + ry;
    if (yy < 0 || yy >= HH) {
#pragma unroll
      for (int j = 0; j < 8; ++j) gr[ry][j] = 0.f;
    } else {
      const float* row = g + yy * WW;
      float4 a = (x0 >= 4) ? *(const float4*)(row + x0 - 4) : make_float4(0, 0, 0, 0);
      float4 m = *(const float4*)(row + x0);
      float4 cq = (x0 + 4 < WW) ? *(const float4*)(row + x0 + 4) : make_float4(0, 0, 0, 0);
      gr[ry][0] = a.z; gr[ry][1] = a.w;
      gr[ry][2] = m.x; gr[ry][3] = m.y; gr[ry][4] = m.z; gr[ry][5] = m.w;
      gr[ry][6] = cq.x; gr[ry][7] = cq.y;
    }
  }
  float hwv[9], pwv[9];
#pragma unroll
  for (int i = 0; i < 9; ++i) { hwv[i] = hw9[i]; pwv[i] = pw9[i]; }
  float hbv = hb[0], pbv = pb[0];

  float hr[3][6];
#pragma unroll
  for (int ry = 0; ry < 3; ++ry) {
    int yy = y - 1 + ry;
    bool rowok = (yy >= 0 && yy < HH);
#pragma unroll
    for (int j = 0; j < 6; ++j) {
      int xx = x0 - 1 + j;
      float acc = hbv;
#pragma unroll
      for (int di = 0; di < 3; ++di)
#pragma unroll
        for (int dj = 0; dj < 3; ++dj)
          acc = fmaf(gr[ry + di][j + dj], hwv[di * 3 + dj], acc);
      hr[ry][j] = (rowok && xx >= 0 && xx < WW) ? fmaxf(acc, 0.f) : 0.f;
    }
  }
  float o[4];
#pragma unroll
  for (int k = 0; k < 4; ++k) {
    float acc = pbv;
#pragma unroll
    for (int di = 0; di < 3; ++di)
#pragma unroll
      for (int dj = 0; dj < 3; ++dj)
        acc = fmaf(hr[di][k + dj], pwv[di * 3 + dj], acc);
    o[k] = 1.f / (1.f + __expf(-acc));
  }
  *(float4*)(p_out + (size_t)b * HW + y * WW + x0) = make_float4(o[0], o[1], o[2], o[3]);
}

// ---------------- shared 7-iteration register-tile body (proven rounds 4/5) ----------------
__device__ __forceinline__ void iter7(float v[8][8], const float p[8][8], const float c[8][8],
                                      int ly, int lx, int lup, int ldn, int llt, int lrt) {
#pragma unroll 1
  for (int it = 0; it < 7; ++it) {
    float th[8], bh[8];
#pragma unroll
    for (int j = 0; j < 8; ++j) { float s = __shfl(v[7][j], lup, 64); th[j] = (ly == 0) ? NEG : s; }
#pragma unroll
    for (int j = 0; j < 8; ++j) { float s = __shfl(v[0][j], ldn, 64); bh[j] = (ly == 7) ? NEG : s; }
    float vm[8][8];
#pragma unroll
    for (int r = 0; r < 8; ++r) {
#pragma unroll
      for (int j = 0; j < 8; ++j) {
        float up = (r == 0) ? th[j] : v[r - 1][j];
        float dn = (r == 7) ? bh[j] : v[r + 1][j];
        vm[r][j] = fmaxf(fmaxf(up, dn), v[r][j]);
      }
    }
#pragma unroll
    for (int r = 0; r < 8; ++r) {
      float sl = __shfl(vm[r][7], llt, 64);
      float sr = __shfl(vm[r][0], lrt, 64);
      float lvm = (lx == 0) ? NEG : sl;
      float rvm = (lx == 7) ? NEG : sr;
      float hm0 = fmaxf(lvm, fmaxf(vm[r][0], vm[r][1]));
      float hm7 = fmaxf(vm[r][6], fmaxf(vm[r][7], rvm));
      v[r][0] = fmaxf(v[r][0], fmaf(p[r][0], hm0, c[r][0]));
#pragma unroll
      for (int j = 1; j < 7; ++j) {
        float hm = fmaxf(vm[r][j - 1], fmaxf(vm[r][j], vm[r][j + 1]));
        v[r][j] = fmaxf(v[r][j], fmaf(p[r][j], hm, c[r][j]));
      }
      v[r][7] = fmaxf(v[r][7], fmaf(p[r][7], hm7, c[r][7]));
    }
  }
}

// ---------------- cooperative all-35-iteration kernel ----------------
// 256 blocks x 256 threads (1 block/CU, ~300 VGPR -> 1 wave/SIMD, all co-resident).
// Wave owns a 64x64 window (clean 48x48); p/c/v pinned in registers across all
// 5 spans. Exchange every 7 iters: interior lanes write clean 48x48 to W_s,
// grid.sync, ring lanes reload their patch. W = [A, B, A, B, out_v]:
// W_{s+1} != W_s and W_{s+2}'s overwrite is fenced by sync_{s+1} => race-free.
__global__ __launch_bounds__(256, 1) void k_vi(const float* __restrict__ p_glob,
                                               const float* __restrict__ X,
                                               float* __restrict__ out_v,
                                               float* __restrict__ bufA,
                                               float* __restrict__ bufB) {
  cg::grid_group grid = cg::this_grid();
  int wid = blockIdx.x * 4 + (threadIdx.x >> 6);
  int lane = threadIdx.x & 63;
  int b = wid >> 4;
  int t = wid & 15;
  int ti = t >> 2, tj = t & 3;
  int ly = lane >> 3, lx = lane & 7;
  int py = ti * 48 - 8 + ly * 8;
  int px = tj * 48 - 8 + lx * 8;
  bool colok = (px >= 0 && px < WW);

  const float* gimg = X + (size_t)b * (2 * HW) + HW;
  const float* pimg = p_glob + (size_t)b * HW;

  float v[8][8], p[8][8], c[8][8];
  // batched loads: p then goal (into c), no consumption between
#pragma unroll
  for (int r = 0; r < 8; ++r) {
    int gy = py + r;
    if (colok && gy >= 0 && gy < HH) {
      *(float4*)&p[r][0] = *(const float4*)(pimg + gy * WW + px);
      *(float4*)&p[r][4] = *(const float4*)(pimg + gy * WW + px + 4);
    }
  }
#pragma unroll
  for (int r = 0; r < 8; ++r) {
    int gy = py + r;
    if (colok && gy >= 0 && gy < HH) {
      *(float4*)&c[r][0] = *(const float4*)(gimg + gy * WW + px);
      *(float4*)&c[r][4] = *(const float4*)(gimg + gy * WW + px + 4);
    }
  }
#pragma unroll
  for (int r = 0; r < 8; ++r) {
    int gy = py + r;
    if (colok && gy >= 0 && gy < HH) {
#pragma unroll
      for (int j = 0; j < 8; ++j) {
        float gg = c[r][j];
        v[r][j] = gg - 1.f;
        c[r][j] = (gg - 1.f) * (1.f - p[r][j]);
      }
    } else {
#pragma unroll
      for (int j = 0; j < 8; ++j) { v[r][j] = NEG; p[r][j] = 0.f; c[r][j] = NEG; }
    }
  }

  int lup = (lane - 8) & 63, ldn = (lane + 8) & 63;
  int llt = (lane - 1) & 63, lrt = (lane + 1) & 63;

  for (int span = 0; span < 5; ++span) {
    iter7(v, p, c, ly, lx, lup, ldn, llt, lrt);

    float* wb = (span == 4) ? out_v : ((span & 1) ? bufB : bufA);
    float* wimg = wb + (size_t)b * HW;
    if (ly >= 1 && ly <= 6 && lx >= 1 && lx <= 6) {
#pragma unroll
      for (int r = 0; r < 8; ++r) {
        *(float4*)(wimg + (py + r) * WW + px) = make_float4(v[r][0], v[r][1], v[r][2], v[r][3]);
        *(float4*)(wimg + (py + r) * WW + px + 4) = make_float4(v[r][4], v[r][5], v[r][6], v[r][7]);
      }
    }
    if (span < 4) {
      grid.sync();
      // ring lanes reload their patch (lies in neighbors' clean regions or OOB)
      if (ly == 0 || ly == 7 || lx == 0 || lx == 7) {
#pragma unroll
        for (int r = 0; r < 8; ++r) {
          int gy = py + r;
          if (colok && gy >= 0 && gy < HH) {
            float4 a = *(const float4*)(wimg + gy * WW + px);
            float4 d = *(const float4*)(wimg + gy * WW + px + 4);
            v[r][0] = a.x; v[r][1] = a.y; v[r][2] = a.z; v[r][3] = a.w;
            v[r][4] = d.x; v[r][5] = d.y; v[r][6] = d.z; v[r][7] = d.w;
          }
          // OOB entries keep NEG (p=0, c=NEG pins them at NEG through iters)
        }
      }
    }
  }
}

// ---------------- fallback span kernel (proven round 5) ----------------
template <int FIRST>
__global__ __launch_bounds__(256, 1) void k_span(const float* __restrict__ v_in,
                                                 const float* __restrict__ p_glob,
                                                 const float* __restrict__ X,
                                                 float* __restrict__ v_out) {
  int wid = blockIdx.x * 4 + (threadIdx.x >> 6);
  int lane = threadIdx.x & 63;
  int b = wid >> 4;
  int t = wid & 15;
  int ti = t >> 2, tj = t & 3;
  int ly = lane >> 3, lx = lane & 7;
  int py = ti * 48 - 8 + ly * 8;
  int px = tj * 48 - 8 + lx * 8;
  bool colok = (px >= 0 && px < WW);

  const float* gimg = X + (size_t)b * (2 * HW) + HW;
  const float* pimg = p_glob + (size_t)b * HW;
  const float* vimg = v_in + (size_t)b * HW;

  float v[8][8], p[8][8], c[8][8];
#pragma unroll
  for (int r = 0; r < 8; ++r) {
    int gy = py + r;
    if (colok && gy >= 0 && gy < HH) {
      *(float4*)&p[r][0] = *(const float4*)(pimg + gy * WW + px);
      *(float4*)&p[r][4] = *(const float4*)(pimg + gy * WW + px + 4);
    }
  }
#pragma unroll
  for (int r = 0; r < 8; ++r) {
    int gy = py + r;
    if (colok && gy >= 0 && gy < HH) {
      *(float4*)&c[r][0] = *(const float4*)(gimg + gy * WW + px);
      *(float4*)&c[r][4] = *(const float4*)(gimg + gy * WW + px + 4);
    }
  }
  if (!FIRST) {
#pragma unroll
    for (int r = 0; r < 8; ++r) {
      int gy = py + r;
      if (colok && gy >= 0 && gy < HH) {
        *(float4*)&v[r][0] = *(const float4*)(vimg + gy * WW + px);
        *(float4*)&v[r][4] = *(const float4*)(vimg + gy * WW + px + 4);
      }
    }
  }
#pragma unroll
  for (int r = 0; r < 8; ++r) {
    int gy = py + r;
    if (colok && gy >= 0 && gy < HH) {
#pragma unroll
      for (int j = 0; j < 8; ++j) {
        float gg = c[r][j];
        if (FIRST) v[r][j] = gg - 1.f;
        c[r][j] = (gg - 1.f) * (1.f - p[r][j]);
      }
    } else {
#pragma unroll
      for (int j = 0; j < 8; ++j) { v[r][j] = NEG; p[r][j] = 0.f; c[r][j] = NEG; }
    }
  }

  int lup = (lane - 8) & 63, ldn = (lane + 8) & 63;
  int llt = (lane - 1) & 63, lrt = (lane + 1) & 63;

  iter7(v, p, c, ly, lx, lup, ldn, llt, lrt);

  if (ly >= 1 && ly <= 6 && lx >= 1 && lx <= 6) {
    float* wimg = v_out + (size_t)b * HW;
#pragma unroll
    for (int r = 0; r < 8; ++r) {
      *(float4*)(wimg + (py + r) * WW + px) = make_float4(v[r][0], v[r][1], v[r][2], v[r][3]);
      *(float4*)(wimg + (py + r) * WW + px + 4) = make_float4(v[r][4], v[r][5], v[r][6], v[r][7]);
    }
  }
}

// ---------------- launch ----------------
extern "C" void kernel_launch(void* const* d_in, const int* in_sizes, int n_in,
                              void* d_out, int out_size, void* d_ws, size_t ws_size,
                              hipStream_t stream) {
  const float* X = (const float*)d_in[0];
  const float* hp_w = (const float*)d_in[1];
  const float* hp_b = (const float*)d_in[2];
  const float* p_w = (const float*)d_in[3];
  const float* p_b = (const float*)d_in[4];

  float* out = (float*)d_out;
  float* out_v = out;          // NPIX floats (final v)
  float* out_p = out + NPIX;   // NPIX floats (p)
  float* bufA = (float*)d_ws;  // NPIX floats
  float* bufB = bufA + NPIX;   // NPIX floats (ws is 256MiB; plenty)

  int nblk = (NPIX / 4 + 255) / 256;
  k_conv_fused<<<nblk, 256, 0, stream>>>(X, hp_w, hp_b, p_w, p_b, out_p);

  const float* p_c = out_p;
  void* args[] = { (void*)&p_c, (void*)&X, (void*)&out_v, (void*)&bufA, (void*)&bufB };
  hipError_t e = hipLaunchCooperativeKernel((const void*)k_vi, dim3(256), dim3(256),
                                            args, 0, stream);
  if (e != hipSuccess) {
    (void)hipGetLastError();  // clear sticky error; fall back to proven span chain
    k_span<1><<<256, 256, 0, stream>>>(X /*unused*/, out_p, X, out_v);
    k_span<0><<<256, 256, 0, stream>>>(out_v, out_p, X, bufA);
    k_span<0><<<256, 256, 0, stream>>>(bufA, out_p, X, out_v);
    k_span<0><<<256, 256, 0, stream>>>(out_v, out_p, X, bufA);
    k_span<0><<<256, 256, 0, stream>>>(bufA, out_p, X, out_v);
  }
}